// Round 6
// baseline (232.583 us; speedup 1.0000x reference)
//
#include <hip/hip_runtime.h>
#include <hip/hip_bf16.h>
#include <stdint.h>

typedef __hip_bfloat16 bf16;
typedef __attribute__((ext_vector_type(8))) short bf16x8;  // 8 bf16 in 4 VGPRs
typedef __attribute__((ext_vector_type(4))) float f32x4;

__device__ inline float bf2f(bf16 v) { return __bfloat162float(v); }
__device__ inline bf16 f2bf(float f) { return __float2bfloat16(f); }

__device__ inline void glds16(const void* g, void* l) {
    __builtin_amdgcn_global_load_lds(
        (const __attribute__((address_space(1))) uint32_t*)g,
        (__attribute__((address_space(3))) uint32_t*)l, 16, 0, 0);
}

// ---- conv_wt body: fp32 W[K][N] -> bf16 Wt[N][K], one 64x64 tile ----
__device__ inline void conv_wt_tile(const float* __restrict__ W,
                                    bf16* __restrict__ Wt, int N, int K,
                                    int bx, int by, int tid, bf16 (*t)[72])
{
    const int n0 = bx * 64, k0 = by * 64;
#pragma unroll
    for (int p = 0; p < 4; ++p) {
        int idx = p * 256 + tid;
        int kr = idx >> 4, c4 = idx & 15;
        float4 f = *(const float4*)(W + (size_t)(k0 + kr) * N + n0 + c4 * 4);
        t[kr][c4 * 4 + 0] = f2bf(f.x); t[kr][c4 * 4 + 1] = f2bf(f.y);
        t[kr][c4 * 4 + 2] = f2bf(f.z); t[kr][c4 * 4 + 3] = f2bf(f.w);
    }
    __syncthreads();
#pragma unroll
    for (int p = 0; p < 2; ++p) {
        int idx = p * 256 + tid;
        int nr = idx >> 3, ch = idx & 7;
        union { bf16x8 v; bf16 e[8]; } u;
#pragma unroll
        for (int j = 0; j < 8; ++j) u.e[j] = t[ch * 8 + j][nr];
        *(bf16x8*)(Wt + (size_t)(n0 + nr) * K + k0 + ch * 8) = u.v;
    }
}

// ---- prep: fused conv_x (blocks 0..2047) + conv_wt w_attn (2048..2815)
//      + conv_wt w_proj (2816..3071) + trig table (3072..3327) ----
__global__ __launch_bounds__(256) void prep(
    const float* __restrict__ x, bf16* __restrict__ xbf,
    const float* __restrict__ w_attn, bf16* __restrict__ wat,
    const float* __restrict__ w_proj, bf16* __restrict__ wpt,
    float2* __restrict__ tab)
{
    __shared__ bf16 t[64][72];
    const int bid = blockIdx.x;
    const int tid = threadIdx.x;
    if (bid < 2048) {
        size_t i = ((size_t)bid * 256 + tid) * 8;
        float4 f0 = *(const float4*)(x + i);
        float4 f1 = *(const float4*)(x + i + 4);
        union { bf16x8 v; bf16 e[8]; } u;
        u.e[0] = f2bf(f0.x); u.e[1] = f2bf(f0.y); u.e[2] = f2bf(f0.z); u.e[3] = f2bf(f0.w);
        u.e[4] = f2bf(f1.x); u.e[5] = f2bf(f1.y); u.e[6] = f2bf(f1.z); u.e[7] = f2bf(f1.w);
        *(bf16x8*)(xbf + i) = u.v;
    } else if (bid < 2816) {
        int idx = bid - 2048;
        conv_wt_tile(w_attn, wat, 3072, 1024, idx % 48, idx / 48, tid, t);
    } else if (bid < 3072) {
        int idx = bid - 2816;
        conv_wt_tile(w_proj, wpt, 1024, 1024, idx % 16, idx / 16, tid, t);
    } else {
        int gid = (bid - 3072) * 256 + tid;      // 65536 entries: (t,p)
        int p = gid & 31, tt = gid >> 5;
        float invf = expf(-(float)(2 * p) * (9.210340371976184f / 64.0f));
        float sn, cs;
        sincosf((float)tt * invf, &sn, &cs);
        tab[gid] = make_float2(cs, sn);
    }
}

// -------- BK=64 m97-structure GEMM, XOR-chunk-swizzled staging --------
// out[M,N] = A(bf16)[M,K] @ Bt(bf16)[N,K]^T + bias.
// Staging: each lane loads 16B of row (lane>>3) at source chunk ((lane&7)^row)&7
// -> LDS linear; frag reads re-apply the XOR -> 2-way banks (free) instead of
// the BK=32 layout's 8-way. Barriers per K: K/64 (halved vs BK=32).
template <bool OUTF32>
__global__ __launch_bounds__(256) void gemm_bt(
    const bf16* __restrict__ A, const bf16* __restrict__ Bt,
    const float* __restrict__ bias, int M, int N, int K, void* __restrict__ outv)
{
    __shared__ __align__(16) bf16 sa[128 * 64];
    __shared__ __align__(16) bf16 sb[128 * 64];

    const int tid  = threadIdx.x;
    const int wave = tid >> 6, lane = tid & 63;
    const int quad = lane >> 4, l16 = lane & 15;
    const int wm = wave >> 1, wn = wave & 1;
    const int row0 = blockIdx.x * 128, n0 = blockIdx.y * 128;

    f32x4 acc[4][4] = {};

    const int srow = lane >> 3;     // row within 8-row group
    const int schk = lane & 7;      // 16B chunk within 64-col row

    for (int k0 = 0; k0 < K; k0 += 64) {
        __syncthreads();
#pragma unroll
        for (int half = 0; half < 2; ++half) {
#pragma unroll
            for (int g = 0; g < 2; ++g) {
                int rowb = half * 64 + wave * 16 + g * 8;
                int row  = rowb + srow;
                glds16(A + (size_t)(row0 + row) * K + k0 + ((schk ^ row) & 7) * 8,
                       &sa[rowb * 64]);
                glds16(Bt + (size_t)(n0 + row) * K + k0 + ((schk ^ row) & 7) * 8,
                       &sb[rowb * 64]);
            }
        }
        __syncthreads();

#pragma unroll
        for (int kk = 0; kk < 2; ++kk) {
            bf16x8 af[4], bfr[4];
#pragma unroll
            for (int mi = 0; mi < 4; ++mi) {
                int row = wm * 64 + mi * 16 + l16;
                af[mi] = *(const bf16x8*)&sa[row * 64 + (((kk * 4 + quad) ^ row) & 7) * 8];
            }
#pragma unroll
            for (int ni = 0; ni < 4; ++ni) {
                int row = wn * 64 + ni * 16 + l16;
                bfr[ni] = *(const bf16x8*)&sb[row * 64 + (((kk * 4 + quad) ^ row) & 7) * 8];
            }
#pragma unroll
            for (int mi = 0; mi < 4; ++mi)
#pragma unroll
                for (int ni = 0; ni < 4; ++ni)
                    acc[mi][ni] = __builtin_amdgcn_mfma_f32_16x16x32_bf16(
                        af[mi], bfr[ni], acc[mi][ni], 0, 0, 0);
        }
    }

#pragma unroll
    for (int ni = 0; ni < 4; ++ni) {
        int col = n0 + wn * 64 + ni * 16 + l16;
        float bvv = bias[col];
#pragma unroll
        for (int mi = 0; mi < 4; ++mi) {
#pragma unroll
            for (int r = 0; r < 4; ++r) {
                int row = row0 + wm * 64 + mi * 16 + quad * 4 + r;
                float v = acc[mi][ni][r] + bvv;
                if (OUTF32) ((float*)outv)[(size_t)row * N + col] = v;
                else        ((bf16*)outv)[(size_t)row * N + col] = f2bf(v);
            }
        }
    }
}

// -------- gemm_qkv: BK=64 GEMM + fused RoPE epilogue ----------------
// cols [0,1024): q -> rope -> qh (scaled 0.125*log2e); [1024,2048): k -> rope -> kh;
// [2048,3072): v -> vc [b*2048+t][1024]. Lane-adjacent cols are rotary pairs ->
// partner via __shfl_xor(v,1). cs/sn from precomputed table (L2-resident).
__global__ __launch_bounds__(256) void gemm_qkv(
    const bf16* __restrict__ A, const bf16* __restrict__ Bt,
    const float* __restrict__ bias, const float2* __restrict__ tab,
    bf16* __restrict__ qh, bf16* __restrict__ kh, bf16* __restrict__ vc)
{
    const int K = 1024;
    __shared__ __align__(16) bf16 sa[128 * 64];
    __shared__ __align__(16) bf16 sb[128 * 64];

    const int tid  = threadIdx.x;
    const int wave = tid >> 6, lane = tid & 63;
    const int quad = lane >> 4, l16 = lane & 15;
    const int wm = wave >> 1, wn = wave & 1;
    const int row0 = blockIdx.x * 128, n0 = blockIdx.y * 128;

    f32x4 acc[4][4] = {};

    const int srow = lane >> 3;
    const int schk = lane & 7;

    for (int k0 = 0; k0 < K; k0 += 64) {
        __syncthreads();
#pragma unroll
        for (int half = 0; half < 2; ++half) {
#pragma unroll
            for (int g = 0; g < 2; ++g) {
                int rowb = half * 64 + wave * 16 + g * 8;
                int row  = rowb + srow;
                glds16(A + (size_t)(row0 + row) * K + k0 + ((schk ^ row) & 7) * 8,
                       &sa[rowb * 64]);
                glds16(Bt + (size_t)(n0 + row) * K + k0 + ((schk ^ row) & 7) * 8,
                       &sb[rowb * 64]);
            }
        }
        __syncthreads();

#pragma unroll
        for (int kk = 0; kk < 2; ++kk) {
            bf16x8 af[4], bfr[4];
#pragma unroll
            for (int mi = 0; mi < 4; ++mi) {
                int row = wm * 64 + mi * 16 + l16;
                af[mi] = *(const bf16x8*)&sa[row * 64 + (((kk * 4 + quad) ^ row) & 7) * 8];
            }
#pragma unroll
            for (int ni = 0; ni < 4; ++ni) {
                int row = wn * 64 + ni * 16 + l16;
                bfr[ni] = *(const bf16x8*)&sb[row * 64 + (((kk * 4 + quad) ^ row) & 7) * 8];
            }
#pragma unroll
            for (int mi = 0; mi < 4; ++mi)
#pragma unroll
                for (int ni = 0; ni < 4; ++ni)
                    acc[mi][ni] = __builtin_amdgcn_mfma_f32_16x16x32_bf16(
                        af[mi], bfr[ni], acc[mi][ni], 0, 0, 0);
        }
    }

    const float QS = 0.125f * 1.44269504088896f;   // fold log2(e) into q scale
#pragma unroll
    for (int ni = 0; ni < 4; ++ni) {
        int col = n0 + wn * 64 + ni * 16 + l16;
        float bvv = bias[col];
        // 16-col lane-group lies inside one 64-col head chunk -> wave-uniform:
        int sec = col >> 10;                       // 0=q, 1=k, 2=v
        int cd  = col & 1023;
        int h   = cd >> 6, d = cd & 63;
        int p   = d >> 1;
        bool odd = (d & 1) != 0;
#pragma unroll
        for (int mi = 0; mi < 4; ++mi) {
#pragma unroll
            for (int r = 0; r < 4; ++r) {
                int row = row0 + wm * 64 + mi * 16 + quad * 4 + r;
                float v = acc[mi][ni][r] + bvv;
                float vp = __shfl_xor(v, 1);       // rotary partner (all lanes exec)
                if (sec == 2) {
                    vc[(size_t)row * 1024 + cd] = f2bf(v);
                } else {
                    int tt = row & 2047, b = row >> 11;
                    float2 cssn = tab[tt * 32 + p];
                    float ro = odd ? (v * cssn.x + vp * cssn.y)
                                   : (v * cssn.x - vp * cssn.y);
                    size_t dst = (((size_t)(b * 16 + h)) * 2048 + tt) * 64 + d;
                    if (sec == 0) qh[dst] = f2bf(ro * QS);
                    else          kh[dst] = f2bf(ro);
                }
            }
        }
    }
}

// ---- transpose_v: vc [b*2048+t][1024] -> vt [bh][64 d][2048 t] ----
__global__ __launch_bounds__(256) void transpose_v(
    const bf16* __restrict__ vc, bf16* __restrict__ vt)
{
    __shared__ bf16 t[64][72];
    const int t0 = blockIdx.x * 64;
    const int bh = blockIdx.y, b = bh >> 4, h = bh & 15;
    const int tid = threadIdx.x;
#pragma unroll
    for (int p = 0; p < 2; ++p) {
        int idx = p * 256 + tid;
        int tr = idx >> 3, ch = idx & 7;
        bf16x8 v = *(const bf16x8*)(vc + ((size_t)(b * 2048 + t0 + tr)) * 1024
                                    + h * 64 + ch * 8);
#pragma unroll
        for (int j = 0; j < 8; ++j) t[tr][ch * 8 + j] = ((const bf16*)&v)[j];
    }
    __syncthreads();
#pragma unroll
    for (int p = 0; p < 2; ++p) {
        int idx = p * 256 + tid;
        int dr = idx >> 3, ch = idx & 7;
        union { bf16x8 v; bf16 e[8]; } u;
#pragma unroll
        for (int j = 0; j < 8; ++j) u.e[j] = t[ch * 8 + j][dr];
        *(bf16x8*)(vt + ((size_t)bh * 64 + dr) * 2048 + t0 + ch * 8) = u.v;
    }
}

// ---- Flash attention, causal. R0-proven staging structure (KVBLK=128,
// single-buffered, 2 barriers/iter) + defer-max (T13, THR=8 log2-units)
// + MFMA row-sum (ones B-operand) + unpaired heavy-first LPT grid:
// 1024 blocks, LDS 50 KiB -> 3 blocks/CU resident + 256-block backfill. ----
__global__ __launch_bounds__(256) void attn_k(
    const bf16* __restrict__ qg, const bf16* __restrict__ kg,
    const bf16* __restrict__ vtg, bf16* __restrict__ y)
{
    __shared__ __align__(16) bf16 sK[128 * 64];     // [key][64d], chunk p=(c^key)&7
    __shared__ __align__(16) bf16 sV[64 * 128];     // [d][128t],  chunk p=(c^d)&15
    __shared__ __align__(16) bf16 pL[4][16][136];   // per-wave P, XOR-chunk swizzle

    const int tid  = threadIdx.x;
    const int wave = tid >> 6, lane = tid & 63;
    const int quad = lane >> 4, l16 = lane & 15;
    const int bh   = blockIdx.x;                    // x = bh -> XCD stationarity
    const int qt   = 31 - (int)blockIdx.y;          // heavy-first (LPT backfill)
    const bf16* Q  = qg  + (size_t)bh * 2048 * 64;
    const bf16* K  = kg  + (size_t)bh * 2048 * 64;
    const bf16* Vt = vtg + (size_t)bh * 64 * 2048;
    const int b = bh >> 4, h = bh & 15;

    const int q0 = qt * 64 + wave * 16;

    bf16x8 aq[2];
    aq[0] = *(const bf16x8*)(Q + (size_t)(q0 + l16) * 64 + quad * 8);
    aq[1] = *(const bf16x8*)(Q + (size_t)(q0 + l16) * 64 + 32 + quad * 8);

    // ones fragment for the row-sum MFMA (bf16 1.0 = 0x3F80)
    union { bf16x8 v; short e[8]; } uo;
#pragma unroll
    for (int j = 0; j < 8; ++j) uo.e[j] = (short)0x3F80;
    const bf16x8 vones = uo.v;

    f32x4 o[4] = {};
    f32x4 ls   = {};                                // row-sum accumulator
    float m_r[4] = {-1e30f, -1e30f, -1e30f, -1e30f};
    const float THR = 8.0f;                         // defer-max threshold (log2 units)

    for (int kt = 0; kt <= q0 + 15; kt += 128) {    // trip count wave-uniform
        __syncthreads();
        // ---- stage K tile: keys kt..kt+127 x 64d ----
#pragma unroll
        for (int c = 0; c < 4; ++c) {
            int key = wave * 32 + c * 8 + (lane >> 3);
            int p = lane & 7;
            glds16(K + (size_t)(kt + key) * 64 + ((p ^ key) & 7) * 8,
                   &sK[(wave * 32 + c * 8) * 64]);
        }
        // ---- stage V^T tile: 64d x t kt..kt+127 ----
#pragma unroll
        for (int c = 0; c < 4; ++c) {
            int d = wave * 16 + c * 4 + (lane >> 4);
            int p = lane & 15;
            glds16(Vt + (size_t)d * 2048 + kt + ((p ^ d) & 15) * 8,
                   &sV[(wave * 16 + c * 4) * 128]);
        }
        __syncthreads();

        const int nlast = min(7, (q0 - kt) >> 4);   // wave-uniform, in [0,7]
        f32x4 sc[8];
        // ---- S' = (Q K^T) * 0.125 * log2e (scale folded into Q) ----
        __builtin_amdgcn_s_setprio(1);
#pragma unroll
        for (int nt = 0; nt < 8; ++nt) {
            if (nt > nlast) continue;
            int key = nt * 16 + l16;
            f32x4 s0 = {};
            bf16x8 bk0 = *(const bf16x8*)&sK[key * 64 + ((quad ^ key) & 7) * 8];
            s0 = __builtin_amdgcn_mfma_f32_16x16x32_bf16(aq[0], bk0, s0, 0, 0, 0);
            bf16x8 bk1 = *(const bf16x8*)&sK[key * 64 + (((4 + quad) ^ key) & 7) * 8];
            sc[nt] = __builtin_amdgcn_mfma_f32_16x16x32_bf16(aq[1], bk1, s0, 0, 0, 0);
        }
        __builtin_amdgcn_s_setprio(0);
        // ---- causal mask: diagonal subtile only ----
        {
            const int diag = (q0 - kt) >> 4;
            if (diag <= 7) {
                int key = kt + diag * 16 + l16;
#pragma unroll
                for (int r = 0; r < 4; ++r) {
                    int row = q0 + quad * 4 + r;
                    if (key > row) sc[diag][r] = -1e30f;
                }
            }
        }
        // ---- online softmax, defer-max: local (in-lane) max + one ballot;
        //      full tree + rescale only when the running max grows > THR ----
        float rowmax[4] = {-1e30f, -1e30f, -1e30f, -1e30f};
#pragma unroll
        for (int nt = 0; nt < 8; ++nt) {
            if (nt > nlast) continue;
#pragma unroll
            for (int r = 0; r < 4; ++r) rowmax[r] = fmaxf(rowmax[r], sc[nt][r]);
        }
        bool okl = (rowmax[0] <= m_r[0] + THR) && (rowmax[1] <= m_r[1] + THR) &&
                   (rowmax[2] <= m_r[2] + THR) && (rowmax[3] <= m_r[3] + THR);
        if (!__all((int)okl)) {
            // rare path: cross-lane max, alpha, rescale o and ls
#pragma unroll
            for (int off = 1; off < 16; off <<= 1)
#pragma unroll
                for (int r = 0; r < 4; ++r)
                    rowmax[r] = fmaxf(rowmax[r], __shfl_xor(rowmax[r], off));
            float alpha[4];
#pragma unroll
            for (int r = 0; r < 4; ++r) {
                float mn = fmaxf(m_r[r], rowmax[r]);
                alpha[r] = exp2f(m_r[r] - mn);
                m_r[r] = mn;
            }
#pragma unroll
            for (int nt = 0; nt < 4; ++nt)
#pragma unroll
                for (int r = 0; r < 4; ++r) o[nt][r] *= alpha[r];
#pragma unroll
            for (int r = 0; r < 4; ++r) ls[r] *= alpha[r];
        }
        // P = exp2(S' - m); bounded by 2^THR = 256 (bf16-safe)
#pragma unroll
        for (int nt = 0; nt < 8; ++nt) {
            if (nt > nlast) continue;
#pragma unroll
            for (int r = 0; r < 4; ++r) sc[nt][r] = exp2f(sc[nt][r] - m_r[r]);
        }

        // ---- P -> per-wave LDS (swizzled), wave-private: no barrier needed ----
#pragma unroll
        for (int nt = 0; nt < 8; ++nt) {
            if (nt > nlast) continue;
            int blk = (2 * nt + (l16 >> 3)) ^ quad;
#pragma unroll
            for (int r = 0; r < 4; ++r)
                pL[wave][quad * 4 + r][blk * 8 + (l16 & 7)] = f2bf(sc[nt][r]);
        }
        if (nlast < 7 && !(nlast & 1)) {            // zero garbage nt-subtile
            int blk = (2 * (nlast + 1) + (l16 >> 3)) ^ quad;
#pragma unroll
            for (int r = 0; r < 4; ++r)
                pL[wave][quad * 4 + r][blk * 8 + (l16 & 7)] = f2bf(0.f);
        }
        // ---- O += P V ; ls += P . 1 (row-sum as extra MFMA column) ----
        __builtin_amdgcn_s_setprio(1);
#pragma unroll
        for (int c = 0; c < 4; ++c) {
            if (c > (nlast >> 1)) continue;
            bf16x8 pa = *(const bf16x8*)&pL[wave][l16][(((4 * c + quad) ^ (l16 >> 2)) * 8)];
            ls = __builtin_amdgcn_mfma_f32_16x16x32_bf16(pa, vones, ls, 0, 0, 0);
#pragma unroll
            for (int dnt = 0; dnt < 4; ++dnt) {
                int d = dnt * 16 + l16;
                int cc = c * 4 + quad;
                bf16x8 vb = *(const bf16x8*)&sV[d * 128 + ((cc ^ d) & 15) * 8];
                o[dnt] = __builtin_amdgcn_mfma_f32_16x16x32_bf16(pa, vb, o[dnt], 0, 0, 0);
            }
        }
        __builtin_amdgcn_s_setprio(0);
    }

    // epilogue
#pragma unroll
    for (int r = 0; r < 4; ++r) {
        float inv = 1.0f / ls[r];
        int qq = q0 + quad * 4 + r;
#pragma unroll
        for (int nt = 0; nt < 4; ++nt) {
            int d = nt * 16 + l16;
            y[((size_t)(b * 2048 + qq)) * 1024 + h * 64 + d] = f2bf(o[nt][r] * inv);
        }
    }
}

extern "C" void kernel_launch(void* const* d_in, const int* in_sizes, int n_in,
                              void* d_out, int out_size, void* d_ws, size_t ws_size,
                              hipStream_t stream) {
    const float* x      = (const float*)d_in[0];
    const float* w_attn = (const float*)d_in[1];
    const float* b_attn = (const float*)d_in[2];
    const float* w_proj = (const float*)d_in[3];
    const float* b_proj = (const float*)d_in[4];
    float* out = (float*)d_out;

    bf16* xbf = (bf16*)d_ws;                         // [4096][1024]
    bf16* wat = xbf + (size_t)4194304;               // [3072][1024] (B^T)
    bf16* wpt = wat + (size_t)3145728;               // [1024][1024] (B^T)
    float2* tab = (float2*)(wpt + (size_t)1048576);  // [2048][32] (cos,sin), 512 KB
    bf16* qh  = wpt + (size_t)1048576 + 262144;      // [bh][2048][64]
    bf16* kh  = qh  + (size_t)4194304;
    bf16* vc  = kh  + (size_t)4194304;               // [b*2048+t][1024]
    bf16* vt  = vc  + (size_t)4194304;               // [bh][64][2048]
    bf16* yws = vt  + (size_t)4194304;               // [4096][1024]

    dim3 blk(256);
    // fused preprocessing: conv_x + conv_wt(w_attn) + conv_wt(w_proj) + trig table
    prep<<<dim3(3328), blk, 0, stream>>>(x, xbf, w_attn, wat, w_proj, wpt, tab);
    // fused qkv GEMM (BK=64) + RoPE epilogue
    gemm_qkv<<<dim3(32, 24), blk, 0, stream>>>(xbf, wat, b_attn, tab, qh, kh, vc);
    transpose_v<<<dim3(32, 32), blk, 0, stream>>>(vc, vt);
    // KVBLK=128 flash attention, heavy-first LPT grid: 3 blocks/CU + backfill
    attn_k<<<dim3(32, 32), blk, 0, stream>>>(qh, kh, vt, yws);
    // proj GEMM (BK=64)
    gemm_bt<true><<<dim3(32, 8), blk, 0, stream>>>(yws, wpt, b_proj,
                                                   4096, 1024, 1024, out);
    (void)in_sizes; (void)n_in; (void)ws_size; (void)out_size;
}

// Round 7
// 210.382 us; speedup vs baseline: 1.1055x; 1.1055x over previous
//
#include <hip/hip_runtime.h>
#include <hip/hip_bf16.h>
#include <stdint.h>

typedef __hip_bfloat16 bf16;
typedef __attribute__((ext_vector_type(8))) short bf16x8;  // 8 bf16 in 4 VGPRs
typedef __attribute__((ext_vector_type(4))) short bf16x4;  // 4 bf16, 8 bytes
typedef __attribute__((ext_vector_type(4))) float f32x4;

__device__ inline float bf2f(bf16 v) { return __bfloat162float(v); }
__device__ inline bf16 f2bf(float f) { return __float2bfloat16(f); }

__device__ inline void glds16(const void* g, void* l) {
    __builtin_amdgcn_global_load_lds(
        (const __attribute__((address_space(1))) uint32_t*)g,
        (__attribute__((address_space(3))) uint32_t*)l, 16, 0, 0);
}

// ---- conv_wt body: fp32 W[K][N] -> bf16 Wt[N][K], one 64x64 tile ----
__device__ inline void conv_wt_tile(const float* __restrict__ W,
                                    bf16* __restrict__ Wt, int N, int K,
                                    int bx, int by, int tid, bf16 (*t)[72])
{
    const int n0 = bx * 64, k0 = by * 64;
#pragma unroll
    for (int p = 0; p < 4; ++p) {
        int idx = p * 256 + tid;
        int kr = idx >> 4, c4 = idx & 15;
        float4 f = *(const float4*)(W + (size_t)(k0 + kr) * N + n0 + c4 * 4);
        t[kr][c4 * 4 + 0] = f2bf(f.x); t[kr][c4 * 4 + 1] = f2bf(f.y);
        t[kr][c4 * 4 + 2] = f2bf(f.z); t[kr][c4 * 4 + 3] = f2bf(f.w);
    }
    __syncthreads();
#pragma unroll
    for (int p = 0; p < 2; ++p) {
        int idx = p * 256 + tid;
        int nr = idx >> 3, ch = idx & 7;
        union { bf16x8 v; bf16 e[8]; } u;
#pragma unroll
        for (int j = 0; j < 8; ++j) u.e[j] = t[ch * 8 + j][nr];
        *(bf16x8*)(Wt + (size_t)(n0 + nr) * K + k0 + ch * 8) = u.v;
    }
}

// ---- prep: fused conv_x (blocks 0..2047) + conv_wt w_attn (2048..2815)
//      + conv_wt w_proj (2816..3071) + trig table (3072..3327) ----
__global__ __launch_bounds__(256) void prep(
    const float* __restrict__ x, bf16* __restrict__ xbf,
    const float* __restrict__ w_attn, bf16* __restrict__ wat,
    const float* __restrict__ w_proj, bf16* __restrict__ wpt,
    float2* __restrict__ tab)
{
    __shared__ bf16 t[64][72];
    const int bid = blockIdx.x;
    const int tid = threadIdx.x;
    if (bid < 2048) {
        size_t i = ((size_t)bid * 256 + tid) * 8;
        float4 f0 = *(const float4*)(x + i);
        float4 f1 = *(const float4*)(x + i + 4);
        union { bf16x8 v; bf16 e[8]; } u;
        u.e[0] = f2bf(f0.x); u.e[1] = f2bf(f0.y); u.e[2] = f2bf(f0.z); u.e[3] = f2bf(f0.w);
        u.e[4] = f2bf(f1.x); u.e[5] = f2bf(f1.y); u.e[6] = f2bf(f1.z); u.e[7] = f2bf(f1.w);
        *(bf16x8*)(xbf + i) = u.v;
    } else if (bid < 2816) {
        int idx = bid - 2048;
        conv_wt_tile(w_attn, wat, 3072, 1024, idx % 48, idx / 48, tid, t);
    } else if (bid < 3072) {
        int idx = bid - 2816;
        conv_wt_tile(w_proj, wpt, 1024, 1024, idx % 16, idx / 16, tid, t);
    } else {
        int gid = (bid - 3072) * 256 + tid;      // 65536 entries: (t,p)
        int p = gid & 31, tt = gid >> 5;
        float invf = expf(-(float)(2 * p) * (9.210340371976184f / 64.0f));
        float sn, cs;
        sincosf((float)tt * invf, &sn, &cs);
        tab[gid] = make_float2(cs, sn);
    }
}

// -------- gemm_qkv: BK=64 GEMM + fused RoPE + fused V-transpose ----------
// cols [0,1024): q -> rope -> qh (scaled 0.125*log2e); [1024,2048): k -> rope -> kh;
// [2048,3072): v -> written DIRECTLY transposed to vt [bh][64 d][2048 t]
// (each lane's 4 acc rows = 4 consecutive t -> one packed 8B store).
__global__ __launch_bounds__(256) void gemm_qkv(
    const bf16* __restrict__ A, const bf16* __restrict__ Bt,
    const float* __restrict__ bias, const float2* __restrict__ tab,
    bf16* __restrict__ qh, bf16* __restrict__ kh, bf16* __restrict__ vt)
{
    const int K = 1024;
    __shared__ __align__(16) bf16 sa[128 * 64];
    __shared__ __align__(16) bf16 sb[128 * 64];

    const int tid  = threadIdx.x;
    const int wave = tid >> 6, lane = tid & 63;
    const int quad = lane >> 4, l16 = lane & 15;
    const int wm = wave >> 1, wn = wave & 1;
    const int row0 = blockIdx.x * 128, n0 = blockIdx.y * 128;

    f32x4 acc[4][4] = {};

    const int srow = lane >> 3;
    const int schk = lane & 7;

    for (int k0 = 0; k0 < K; k0 += 64) {
        __syncthreads();
#pragma unroll
        for (int half = 0; half < 2; ++half) {
#pragma unroll
            for (int g = 0; g < 2; ++g) {
                int rowb = half * 64 + wave * 16 + g * 8;
                int row  = rowb + srow;
                glds16(A + (size_t)(row0 + row) * K + k0 + ((schk ^ row) & 7) * 8,
                       &sa[rowb * 64]);
                glds16(Bt + (size_t)(n0 + row) * K + k0 + ((schk ^ row) & 7) * 8,
                       &sb[rowb * 64]);
            }
        }
        __syncthreads();

#pragma unroll
        for (int kk = 0; kk < 2; ++kk) {
            bf16x8 af[4], bfr[4];
#pragma unroll
            for (int mi = 0; mi < 4; ++mi) {
                int row = wm * 64 + mi * 16 + l16;
                af[mi] = *(const bf16x8*)&sa[row * 64 + (((kk * 4 + quad) ^ row) & 7) * 8];
            }
#pragma unroll
            for (int ni = 0; ni < 4; ++ni) {
                int row = wn * 64 + ni * 16 + l16;
                bfr[ni] = *(const bf16x8*)&sb[row * 64 + (((kk * 4 + quad) ^ row) & 7) * 8];
            }
#pragma unroll
            for (int mi = 0; mi < 4; ++mi)
#pragma unroll
                for (int ni = 0; ni < 4; ++ni)
                    acc[mi][ni] = __builtin_amdgcn_mfma_f32_16x16x32_bf16(
                        af[mi], bfr[ni], acc[mi][ni], 0, 0, 0);
        }
    }

    const float QS = 0.125f * 1.44269504088896f;   // fold log2(e) into q scale
#pragma unroll
    for (int ni = 0; ni < 4; ++ni) {
        int col = n0 + wn * 64 + ni * 16 + l16;
        float bvv = bias[col];
        // 16-col lane-group lies inside one 64-col head chunk -> sec,h wave-uniform:
        int sec = col >> 10;                       // 0=q, 1=k, 2=v
        int cd  = col & 1023;
        int h   = cd >> 6, d = cd & 63;
        if (sec == 2) {
            // v: write transposed, 4 consecutive t per lane -> packed 8B store
#pragma unroll
            for (int mi = 0; mi < 4; ++mi) {
                int trow = row0 + wm * 64 + mi * 16 + quad * 4;
                int tt0 = trow & 2047, bb = trow >> 11;
                union { bf16x4 v; bf16 e[4]; } pv;
#pragma unroll
                for (int r = 0; r < 4; ++r) pv.e[r] = f2bf(acc[mi][ni][r] + bvv);
                *(bf16x4*)(vt + ((size_t)((bb * 16 + h) * 64 + d)) * 2048 + tt0) = pv.v;
            }
        } else {
            int p   = d >> 1;
            bool odd = (d & 1) != 0;
#pragma unroll
            for (int mi = 0; mi < 4; ++mi) {
#pragma unroll
                for (int r = 0; r < 4; ++r) {
                    int row = row0 + wm * 64 + mi * 16 + quad * 4 + r;
                    float v = acc[mi][ni][r] + bvv;
                    float vp = __shfl_xor(v, 1);   // rotary partner (wave-uniform branch)
                    int tt = row & 2047, b = row >> 11;
                    float2 cssn = tab[tt * 32 + p];
                    float ro = odd ? (v * cssn.x + vp * cssn.y)
                                   : (v * cssn.x - vp * cssn.y);
                    size_t dst = (((size_t)(b * 16 + h)) * 2048 + tt) * 64 + d;
                    if (sec == 0) qh[dst] = f2bf(ro * QS);
                    else          kh[dst] = f2bf(ro);
                }
            }
        }
    }
}

// -------- gemm_proj: out(f32)[4096,1024] = A[4096,1024] @ Bt[1024,1024]^T + bias --
// BM=64 x BN=128 tiles -> grid (64,8) = 512 blocks = 2 blocks/CU, 8 waves/CU
// (the old 128x128 grid was 256 blocks = 1 block/CU = latency-starved).
// 4 waves arranged 1M x 4N: each wave 64 rows x 32 cols (acc[4][2]).
__global__ __launch_bounds__(256) void gemm_proj(
    const bf16* __restrict__ A, const bf16* __restrict__ Bt,
    const float* __restrict__ bias, float* __restrict__ out)
{
    const int N = 1024, K = 1024;
    __shared__ __align__(16) bf16 sa[64 * 64];
    __shared__ __align__(16) bf16 sb[128 * 64];

    const int tid  = threadIdx.x;
    const int wave = tid >> 6, lane = tid & 63;
    const int quad = lane >> 4, l16 = lane & 15;
    const int row0 = blockIdx.x * 64, n0 = blockIdx.y * 128;

    f32x4 acc[4][2] = {};

    const int srow = lane >> 3;
    const int schk = lane & 7;

    for (int k0 = 0; k0 < K; k0 += 64) {
        __syncthreads();
#pragma unroll
        for (int g = 0; g < 2; ++g) {               // A: 64 rows, 16/wave
            int rowb = wave * 16 + g * 8;
            int row  = rowb + srow;
            glds16(A + (size_t)(row0 + row) * K + k0 + ((schk ^ row) & 7) * 8,
                   &sa[rowb * 64]);
        }
#pragma unroll
        for (int g = 0; g < 4; ++g) {               // B: 128 rows, 32/wave
            int rowb = wave * 32 + g * 8;
            int row  = rowb + srow;
            glds16(Bt + (size_t)(n0 + row) * K + k0 + ((schk ^ row) & 7) * 8,
                   &sb[rowb * 64]);
        }
        __syncthreads();

#pragma unroll
        for (int kk = 0; kk < 2; ++kk) {
            bf16x8 af[4], bfr[2];
#pragma unroll
            for (int mi = 0; mi < 4; ++mi) {
                int row = mi * 16 + l16;
                af[mi] = *(const bf16x8*)&sa[row * 64 + (((kk * 4 + quad) ^ row) & 7) * 8];
            }
#pragma unroll
            for (int ni = 0; ni < 2; ++ni) {
                int row = wave * 32 + ni * 16 + l16;
                bfr[ni] = *(const bf16x8*)&sb[row * 64 + (((kk * 4 + quad) ^ row) & 7) * 8];
            }
#pragma unroll
            for (int mi = 0; mi < 4; ++mi)
#pragma unroll
                for (int ni = 0; ni < 2; ++ni)
                    acc[mi][ni] = __builtin_amdgcn_mfma_f32_16x16x32_bf16(
                        af[mi], bfr[ni], acc[mi][ni], 0, 0, 0);
        }
    }

#pragma unroll
    for (int ni = 0; ni < 2; ++ni) {
        int col = n0 + wave * 32 + ni * 16 + l16;
        float bvv = bias[col];
#pragma unroll
        for (int mi = 0; mi < 4; ++mi) {
#pragma unroll
            for (int r = 0; r < 4; ++r) {
                int row = row0 + mi * 16 + quad * 4 + r;
                out[(size_t)row * N + col] = acc[mi][ni][r] + bvv;
            }
        }
    }
}

// ---- Flash attention, causal. R0-proven staging structure (KVBLK=128,
// single-buffered, 2 barriers/iter) + defer-max (T13, THR=8 log2-units)
// + MFMA row-sum (ones B-operand) + unpaired heavy-first LPT grid:
// 1024 blocks, LDS 50 KiB -> 3 blocks/CU resident + 256-block backfill. ----
__global__ __launch_bounds__(256) void attn_k(
    const bf16* __restrict__ qg, const bf16* __restrict__ kg,
    const bf16* __restrict__ vtg, bf16* __restrict__ y)
{
    __shared__ __align__(16) bf16 sK[128 * 64];     // [key][64d], chunk p=(c^key)&7
    __shared__ __align__(16) bf16 sV[64 * 128];     // [d][128t],  chunk p=(c^d)&15
    __shared__ __align__(16) bf16 pL[4][16][136];   // per-wave P, XOR-chunk swizzle

    const int tid  = threadIdx.x;
    const int wave = tid >> 6, lane = tid & 63;
    const int quad = lane >> 4, l16 = lane & 15;
    const int bh   = blockIdx.x;                    // x = bh -> XCD stationarity
    const int qt   = 31 - (int)blockIdx.y;          // heavy-first (LPT backfill)
    const bf16* Q  = qg  + (size_t)bh * 2048 * 64;
    const bf16* K  = kg  + (size_t)bh * 2048 * 64;
    const bf16* Vt = vtg + (size_t)bh * 64 * 2048;
    const int b = bh >> 4, h = bh & 15;

    const int q0 = qt * 64 + wave * 16;

    bf16x8 aq[2];
    aq[0] = *(const bf16x8*)(Q + (size_t)(q0 + l16) * 64 + quad * 8);
    aq[1] = *(const bf16x8*)(Q + (size_t)(q0 + l16) * 64 + 32 + quad * 8);

    // ones fragment for the row-sum MFMA (bf16 1.0 = 0x3F80)
    union { bf16x8 v; short e[8]; } uo;
#pragma unroll
    for (int j = 0; j < 8; ++j) uo.e[j] = (short)0x3F80;
    const bf16x8 vones = uo.v;

    f32x4 o[4] = {};
    f32x4 ls   = {};                                // row-sum accumulator
    float m_r[4] = {-1e30f, -1e30f, -1e30f, -1e30f};
    const float THR = 8.0f;                         // defer-max threshold (log2 units)

    for (int kt = 0; kt <= q0 + 15; kt += 128) {    // trip count wave-uniform
        __syncthreads();
        // ---- stage K tile: keys kt..kt+127 x 64d ----
#pragma unroll
        for (int c = 0; c < 4; ++c) {
            int key = wave * 32 + c * 8 + (lane >> 3);
            int p = lane & 7;
            glds16(K + (size_t)(kt + key) * 64 + ((p ^ key) & 7) * 8,
                   &sK[(wave * 32 + c * 8) * 64]);
        }
        // ---- stage V^T tile: 64d x t kt..kt+127 ----
#pragma unroll
        for (int c = 0; c < 4; ++c) {
            int d = wave * 16 + c * 4 + (lane >> 4);
            int p = lane & 15;
            glds16(Vt + (size_t)d * 2048 + kt + ((p ^ d) & 15) * 8,
                   &sV[(wave * 16 + c * 4) * 128]);
        }
        __syncthreads();

        const int nlast = min(7, (q0 - kt) >> 4);   // wave-uniform, in [0,7]
        f32x4 sc[8];
        // ---- S' = (Q K^T) * 0.125 * log2e (scale folded into Q) ----
        __builtin_amdgcn_s_setprio(1);
#pragma unroll
        for (int nt = 0; nt < 8; ++nt) {
            if (nt > nlast) continue;
            int key = nt * 16 + l16;
            f32x4 s0 = {};
            bf16x8 bk0 = *(const bf16x8*)&sK[key * 64 + ((quad ^ key) & 7) * 8];
            s0 = __builtin_amdgcn_mfma_f32_16x16x32_bf16(aq[0], bk0, s0, 0, 0, 0);
            bf16x8 bk1 = *(const bf16x8*)&sK[key * 64 + (((4 + quad) ^ key) & 7) * 8];
            sc[nt] = __builtin_amdgcn_mfma_f32_16x16x32_bf16(aq[1], bk1, s0, 0, 0, 0);
        }
        __builtin_amdgcn_s_setprio(0);
        // ---- causal mask: diagonal subtile only ----
        {
            const int diag = (q0 - kt) >> 4;
            if (diag <= 7) {
                int key = kt + diag * 16 + l16;
#pragma unroll
                for (int r = 0; r < 4; ++r) {
                    int row = q0 + quad * 4 + r;
                    if (key > row) sc[diag][r] = -1e30f;
                }
            }
        }
        // ---- online softmax, defer-max: local (in-lane) max + one ballot;
        //      full tree + rescale only when the running max grows > THR ----
        float rowmax[4] = {-1e30f, -1e30f, -1e30f, -1e30f};
#pragma unroll
        for (int nt = 0; nt < 8; ++nt) {
            if (nt > nlast) continue;
#pragma unroll
            for (int r = 0; r < 4; ++r) rowmax[r] = fmaxf(rowmax[r], sc[nt][r]);
        }
        bool okl = (rowmax[0] <= m_r[0] + THR) && (rowmax[1] <= m_r[1] + THR) &&
                   (rowmax[2] <= m_r[2] + THR) && (rowmax[3] <= m_r[3] + THR);
        if (!__all((int)okl)) {
            // rare path: cross-lane max, alpha, rescale o and ls
#pragma unroll
            for (int off = 1; off < 16; off <<= 1)
#pragma unroll
                for (int r = 0; r < 4; ++r)
                    rowmax[r] = fmaxf(rowmax[r], __shfl_xor(rowmax[r], off));
            float alpha[4];
#pragma unroll
            for (int r = 0; r < 4; ++r) {
                float mn = fmaxf(m_r[r], rowmax[r]);
                alpha[r] = exp2f(m_r[r] - mn);
                m_r[r] = mn;
            }
#pragma unroll
            for (int nt = 0; nt < 4; ++nt)
#pragma unroll
                for (int r = 0; r < 4; ++r) o[nt][r] *= alpha[r];
#pragma unroll
            for (int r = 0; r < 4; ++r) ls[r] *= alpha[r];
        }
        // P = exp2(S' - m); bounded by 2^THR = 256 (bf16-safe)
#pragma unroll
        for (int nt = 0; nt < 8; ++nt) {
            if (nt > nlast) continue;
#pragma unroll
            for (int r = 0; r < 4; ++r) sc[nt][r] = exp2f(sc[nt][r] - m_r[r]);
        }

        // ---- P -> per-wave LDS (swizzled), wave-private: no barrier needed ----
#pragma unroll
        for (int nt = 0; nt < 8; ++nt) {
            if (nt > nlast) continue;
            int blk = (2 * nt + (l16 >> 3)) ^ quad;
#pragma unroll
            for (int r = 0; r < 4; ++r)
                pL[wave][quad * 4 + r][blk * 8 + (l16 & 7)] = f2bf(sc[nt][r]);
        }
        if (nlast < 7 && !(nlast & 1)) {            // zero garbage nt-subtile
            int blk = (2 * (nlast + 1) + (l16 >> 3)) ^ quad;
#pragma unroll
            for (int r = 0; r < 4; ++r)
                pL[wave][quad * 4 + r][blk * 8 + (l16 & 7)] = f2bf(0.f);
        }
        // ---- O += P V ; ls += P . 1 (row-sum as extra MFMA column) ----
        __builtin_amdgcn_s_setprio(1);
#pragma unroll
        for (int c = 0; c < 4; ++c) {
            if (c > (nlast >> 1)) continue;
            bf16x8 pa = *(const bf16x8*)&pL[wave][l16][(((4 * c + quad) ^ (l16 >> 2)) * 8)];
            ls = __builtin_amdgcn_mfma_f32_16x16x32_bf16(pa, vones, ls, 0, 0, 0);
#pragma unroll
            for (int dnt = 0; dnt < 4; ++dnt) {
                int d = dnt * 16 + l16;
                int cc = c * 4 + quad;
                bf16x8 vb = *(const bf16x8*)&sV[d * 128 + ((cc ^ d) & 15) * 8];
                o[dnt] = __builtin_amdgcn_mfma_f32_16x16x32_bf16(pa, vb, o[dnt], 0, 0, 0);
            }
        }
        __builtin_amdgcn_s_setprio(0);
    }

    // epilogue
#pragma unroll
    for (int r = 0; r < 4; ++r) {
        float inv = 1.0f / ls[r];
        int qq = q0 + quad * 4 + r;
#pragma unroll
        for (int nt = 0; nt < 4; ++nt) {
            int d = nt * 16 + l16;
            y[((size_t)(b * 2048 + qq)) * 1024 + h * 64 + d] = f2bf(o[nt][r] * inv);
        }
    }
}

extern "C" void kernel_launch(void* const* d_in, const int* in_sizes, int n_in,
                              void* d_out, int out_size, void* d_ws, size_t ws_size,
                              hipStream_t stream) {
    const float* x      = (const float*)d_in[0];
    const float* w_attn = (const float*)d_in[1];
    const float* b_attn = (const float*)d_in[2];
    const float* w_proj = (const float*)d_in[3];
    const float* b_proj = (const float*)d_in[4];
    float* out = (float*)d_out;

    bf16* xbf = (bf16*)d_ws;                         // [4096][1024]
    bf16* wat = xbf + (size_t)4194304;               // [3072][1024] (B^T)
    bf16* wpt = wat + (size_t)3145728;               // [1024][1024] (B^T)
    float2* tab = (float2*)(wpt + (size_t)1048576);  // [2048][32] (cos,sin), 512 KB
    bf16* qh  = wpt + (size_t)1048576 + 262144;      // [bh][2048][64]
    bf16* kh  = qh  + (size_t)4194304;
    bf16* vt  = kh  + (size_t)4194304;               // [bh][64][2048]
    bf16* yws = vt  + (size_t)4194304;               // [4096][1024]

    dim3 blk(256);
    // fused preprocessing: conv_x + conv_wt(w_attn) + conv_wt(w_proj) + trig table
    prep<<<dim3(3328), blk, 0, stream>>>(x, xbf, w_attn, wat, w_proj, wpt, tab);
    // fused qkv GEMM (BK=64) + RoPE + direct V-transpose (replaces transpose_v)
    gemm_qkv<<<dim3(32, 24), blk, 0, stream>>>(xbf, wat, b_attn, tab, qh, kh, vt);
    // KVBLK=128 flash attention, heavy-first LPT grid: 3 blocks/CU + backfill
    attn_k<<<dim3(32, 32), blk, 0, stream>>>(qh, kh, vt, yws);
    // proj GEMM: BM=64 tiles -> 512 blocks (2/CU, 8 waves/CU)
    gemm_proj<<<dim3(64, 8), blk, 0, stream>>>(yws, wpt, b_proj, out);
    (void)in_sizes; (void)n_in; (void)ws_size; (void)out_size;
}